// Round 4
// baseline (1176.480 us; speedup 1.0000x reference)
//
#include <hip/hip_runtime.h>
#include <math.h>

// ---------------------------------------------------------------------------
// MPNCOV / iSQRT-COV, split-bf16 MFMA implementation.
//   B=256, C=256, M=196.  All matrices stored as bf16 (hi, lo) pairs so that
//   a@b is computed as 4 MFMA terms with fp32 accumulation (~2^-16 rel err).
//   Every matrix in the NS chain is symmetric -> GEMM operands are staged
//   k-major by reading ROWS (coalesced, raw bytes via global_load_lds w=16),
//   and only 3 of 4 128x128 tiles are computed (t01 mirror-written from the
//   same fp32 values => outputs stay exactly symmetric).
// ---------------------------------------------------------------------------

#define BB 256
#define CC 256
#define MN 196
#define KP 224            // X padded K (7 * 32) for the cov GEMM
#define TRI 32896

typedef __attribute__((ext_vector_type(8))) short short8;   // 8 bf16 = 4 VGPR
typedef __attribute__((ext_vector_type(4))) float f32x4;

__device__ __forceinline__ unsigned short f2bf(float x) {   // RNE fp32->bf16
    unsigned u = __float_as_uint(x);
    u += 0x7fffu + ((u >> 16) & 1u);
    return (unsigned short)(u >> 16);
}
__device__ __forceinline__ float bf2f(unsigned short h) {
    return __uint_as_float(((unsigned)h) << 16);
}
__device__ __forceinline__ void async16(const void* g, void* l) {
    __builtin_amdgcn_global_load_lds(
        (const __attribute__((address_space(1))) unsigned char*)g,
        (__attribute__((address_space(3))) unsigned char*)l, 16, 0, 0);
}

// ---------------------------------------------------------------------------
// Per-row sum and sum-of-squares: one wave per (b,c) row of 196 floats.
// ---------------------------------------------------------------------------
__global__ __launch_bounds__(256) void meanpow_kernel(const float* __restrict__ x,
                                                      float* __restrict__ mu,
                                                      float* __restrict__ pw) {
    int wave = (blockIdx.x * 256 + threadIdx.x) >> 6;
    int lane = threadIdx.x & 63;
    const float* row = x + (size_t)wave * MN;
    float a0 = row[lane], a1 = row[lane + 64], a2 = row[lane + 128];
    float a3 = (lane < MN - 192) ? row[lane + 192] : 0.0f;
    float s  = a0 + a1 + a2 + a3;
    float ss = a0 * a0 + a1 * a1 + a2 * a2 + a3 * a3;
    #pragma unroll
    for (int off = 32; off > 0; off >>= 1) {
        s  += __shfl_down(s, off, 64);
        ss += __shfl_down(ss, off, 64);
    }
    if (lane == 0) { mu[wave] = s * (1.0f / MN); pw[wave] = ss; }
}

// ---------------------------------------------------------------------------
// normA[b] = trace(cov) = sum_c ( pw_c/M - mu_c^2 );  store 1/n, sqrt, 1/sqrt
// ---------------------------------------------------------------------------
__global__ __launch_bounds__(256) void norm_kernel(const float* __restrict__ mu,
                                                   const float* __restrict__ pw,
                                                   float* __restrict__ inv,
                                                   float* __restrict__ snorm,
                                                   float* __restrict__ invs) {
    __shared__ float red[256];
    int b = blockIdx.x, i = threadIdx.x;
    float m = mu[b * CC + i];
    red[i] = pw[b * CC + i] * (1.0f / MN) - m * m;
    __syncthreads();
    for (int s = 128; s > 0; s >>= 1) {
        if (i < s) red[i] += red[i + s];
        __syncthreads();
    }
    if (i == 0) {
        float n = red[0];
        inv[b] = 1.0f / n;
        float sq = sqrtf(n);
        snorm[b] = sq;
        invs[b] = 1.0f / sq;
    }
}

// ---------------------------------------------------------------------------
// Split x into zero-padded bf16 hi/lo:  xp[bl][256 rows][224 k]
// ---------------------------------------------------------------------------
__global__ __launch_bounds__(256) void splitx_kernel(const float* __restrict__ x,
                                                     unsigned short* __restrict__ xh,
                                                     unsigned short* __restrict__ xl,
                                                     int b0) {
    int t = blockIdx.x * 256 + threadIdx.x;      // row*56 + k4, t < 14336
    int row = t / 56;
    int k4 = t - row * 56;
    const float* xr = x + ((size_t)(b0 + blockIdx.y) * CC + row) * MN;
    unsigned long long ph = 0, pl = 0;
    #pragma unroll
    for (int i = 0; i < 4; ++i) {
        int k = k4 * 4 + i;
        float xv = (k < MN) ? xr[k] : 0.0f;
        unsigned short h = f2bf(xv);
        unsigned short l = f2bf(xv - bf2f(h));
        ph |= ((unsigned long long)h) << (16 * i);
        pl |= ((unsigned long long)l) << (16 * i);
    }
    size_t o = ((size_t)blockIdx.y * CC + row) * KP + k4 * 4;
    *(unsigned long long*)&xh[o] = ph;
    *(unsigned long long*)&xl[o] = pl;
}

// ---------------------------------------------------------------------------
// Split-bf16 MFMA GEMM.  MODE 0: cov->A epilogue (K=224, mu/inv),
// MODE 1: NS epilogue  C = al*(A@B) + be*E + diag*I, al/be opt * Sg[bg],
//         output split to hi/lo, t01 mirrored.
// MODE 2: FINAL  out(triu fp32) = A@B.
// 128x128 tile, 4 waves, wave = 64x64 = 4x4 frags of 16x16x32 bf16 MFMA.
// ---------------------------------------------------------------------------
template <int MODE>
__global__ __launch_bounds__(256, 3) void mm_kernel(
    const unsigned short* __restrict__ Ahg, const unsigned short* __restrict__ Alg,
    const unsigned short* __restrict__ Bhg, const unsigned short* __restrict__ Blg,
    const unsigned short* __restrict__ Ehg, const unsigned short* __restrict__ Elg,
    void* __restrict__ Cho, void* __restrict__ Clo,
    const float* __restrict__ mu, const float* __restrict__ inv,
    const float* __restrict__ Sg,
    float alpha0, float beta0, float diag_add, int b0)
{
    constexpr int KD = (MODE == 0) ? KP : CC;
    constexpr int NK = KD / 32;
    __shared__ __align__(16) unsigned short Ah[128 * 32];
    __shared__ __align__(16) unsigned short Al[128 * 32];
    __shared__ __align__(16) unsigned short Bh[128 * 32];
    __shared__ __align__(16) unsigned short Bl[128 * 32];
    __shared__ float eps[4][64 * 17];

    const int bl = blockIdx.x / 3;
    const int t  = blockIdx.x - 3 * bl;
    const int bg = b0 + bl;
    const int ti = (t == 2) ? 1 : 0;
    const int tj = (t == 0) ? 0 : 1;
    const int tid = threadIdx.x;
    const int w = tid >> 6, lane = tid & 63;
    const int wr = w >> 1, wc = w & 1;
    const int m15 = lane & 15, q = lane >> 4;
    const int srow = lane >> 2;          // staging: 16-row chunk, 4 lanes/row
    const int scol = (lane & 3) * 8;     // staging: 8-bf16 (16B) sub-chunk

    // this wave's staging tile — wave-uniform branch select (NO pointer
    // arrays: arrays of LDS pointers fail to compile on gfx950)
    const size_t aoff = (size_t)bl * CC * KD + (size_t)(ti * 128) * KD;
    const size_t boff = (size_t)bl * CC * KD + (size_t)(tj * 128) * KD;
    const unsigned short* gsrc;
    unsigned short* ldst;
    if (w == 0)      { gsrc = Ahg + aoff; ldst = Ah; }
    else if (w == 1) { gsrc = Alg + aoff; ldst = Al; }
    else if (w == 2) { gsrc = Bhg + boff; ldst = Bh; }
    else             { gsrc = Blg + boff; ldst = Bl; }

    f32x4 acc[4][4];
    #pragma unroll
    for (int mi = 0; mi < 4; ++mi)
        #pragma unroll
        for (int ni = 0; ni < 4; ++ni) acc[mi][ni] = (f32x4){0.f, 0.f, 0.f, 0.f};

    #pragma unroll 1
    for (int ks = 0; ks < NK; ++ks) {
        const int k0 = ks * 32;
        __syncthreads();
        #pragma unroll
        for (int tt = 0; tt < 8; ++tt)
            async16(gsrc + (size_t)(tt * 16 + srow) * KD + k0 + scol,
                    ldst + tt * 16 * 32);
        __syncthreads();
        short8 fah[4], fal[4], fbh[4], fbl[4];
        #pragma unroll
        for (int f = 0; f < 4; ++f) {
            int ra = (wr * 64 + f * 16 + m15) * 32 + q * 8;
            int rb = (wc * 64 + f * 16 + m15) * 32 + q * 8;
            fah[f] = *(const short8*)&Ah[ra];
            fal[f] = *(const short8*)&Al[ra];
            fbh[f] = *(const short8*)&Bh[rb];
            fbl[f] = *(const short8*)&Bl[rb];
        }
        #pragma unroll
        for (int mi = 0; mi < 4; ++mi)
            #pragma unroll
            for (int ni = 0; ni < 4; ++ni) {
                acc[mi][ni] = __builtin_amdgcn_mfma_f32_16x16x32_bf16(fal[mi], fbl[ni], acc[mi][ni], 0, 0, 0);
                acc[mi][ni] = __builtin_amdgcn_mfma_f32_16x16x32_bf16(fal[mi], fbh[ni], acc[mi][ni], 0, 0, 0);
                acc[mi][ni] = __builtin_amdgcn_mfma_f32_16x16x32_bf16(fah[mi], fbl[ni], acc[mi][ni], 0, 0, 0);
                acc[mi][ni] = __builtin_amdgcn_mfma_f32_16x16x32_bf16(fah[mi], fbh[ni], acc[mi][ni], 0, 0, 0);
            }
    }

    // ---------------- epilogue: per 16-col band through padded LDS ----------
    float* ep = eps[w];
    unsigned short* Ch = (unsigned short*)Cho;
    unsigned short* Cl = (unsigned short*)Clo;

    float ivv = 0.f, ivm = 0.f, al = alpha0, be = beta0;
    if (MODE == 0) { ivv = inv[bg]; ivm = ivv * (1.0f / MN); }
    if (MODE == 1 && Sg != nullptr) { float s = Sg[bg]; al *= s; be *= s; }

    #pragma unroll 1
    for (int ni = 0; ni < 4; ++ni) {
        // dump 64x16 fp32 band (C/D layout: row = q*4+r, col = m15)
        #pragma unroll
        for (int mi = 0; mi < 4; ++mi)
            #pragma unroll
            for (int r = 0; r < 4; ++r)
                ep[(mi * 16 + q * 4 + r) * 17 + m15] = acc[mi][ni][r];
        __syncthreads();   // also orders LDS RAW within the wave

        // ---- direct tile: lane = row, 16 cols ----
        {
            int gr = ti * 128 + wr * 64 + lane;
            int gc = tj * 128 + wc * 64 + ni * 16;
            float v[16];
            #pragma unroll
            for (int c = 0; c < 16; ++c) v[c] = ep[lane * 17 + c];

            if (MODE == 2) {
                float* outp = (float*)Cho;
                int rowbase = gr * CC - (gr * (gr - 1)) / 2 - gr;
                float* ob = outp + (size_t)bg * TRI + rowbase;
                #pragma unroll
                for (int c = 0; c < 16; ++c) {
                    int gcol = gc + c;
                    if (gcol >= gr) ob[gcol] = v[c];
                }
            } else {
                float val[16];
                if (MODE == 0) {
                    float mr = mu[bg * CC + gr];
                    const float* mcp = &mu[bg * CC + gc];
                    #pragma unroll
                    for (int c = 0; c < 16; ++c)
                        val[c] = v[c] * ivm - mr * mcp[c] * ivv;
                } else {
                    float e[16];
                    if (Ehg != nullptr) {
                        size_t eb = (size_t)bl * CC * CC + (size_t)gr * CC + gc;
                        #pragma unroll
                        for (int c = 0; c < 16; ++c)
                            e[c] = bf2f((unsigned short)((const short*)Ehg)[eb + c]) +
                                   bf2f((unsigned short)((const short*)Elg)[eb + c]);
                    } else {
                        #pragma unroll
                        for (int c = 0; c < 16; ++c) e[c] = 0.f;
                    }
                    #pragma unroll
                    for (int c = 0; c < 16; ++c) {
                        val[c] = al * v[c] + be * e[c];
                        if (gr == gc + c) val[c] += diag_add;
                    }
                }
                short8 h0, h1, l0, l1;
                #pragma unroll
                for (int c = 0; c < 8; ++c) {
                    unsigned short h = f2bf(val[c]);
                    h0[c] = (short)h; l0[c] = (short)f2bf(val[c] - bf2f(h));
                    unsigned short h2 = f2bf(val[c + 8]);
                    h1[c] = (short)h2; l1[c] = (short)f2bf(val[c + 8] - bf2f(h2));
                }
                size_t cb = (size_t)bl * CC * CC + (size_t)gr * CC + gc;
                *(short8*)&Ch[cb] = h0; *(short8*)&Ch[cb + 8] = h1;
                *(short8*)&Cl[cb] = l0; *(short8*)&Cl[cb + 8] = l1;
            }
        }

        // ---- mirror tile (t01 only, MODE 0/1): transposed read ----
        if (MODE != 2 && ti != tj) {
            float tv[16];
            #pragma unroll
            for (int s = 0; s < 16; ++s) tv[s] = ep[(q * 16 + s) * 17 + m15];
            int grm = tj * 128 + wc * 64 + ni * 16 + m15;
            int gcm = ti * 128 + wr * 64 + q * 16;
            float val[16];
            if (MODE == 0) {
                float mr = mu[bg * CC + grm];
                const float* mcp = &mu[bg * CC + gcm];
                #pragma unroll
                for (int s = 0; s < 16; ++s)
                    val[s] = tv[s] * ivm - mr * mcp[s] * ivv;
            } else {
                float e[16];
                if (Ehg != nullptr) {
                    size_t eb = (size_t)bl * CC * CC + (size_t)grm * CC + gcm;
                    #pragma unroll
                    for (int s = 0; s < 16; ++s)
                        e[s] = bf2f((unsigned short)((const short*)Ehg)[eb + s]) +
                               bf2f((unsigned short)((const short*)Elg)[eb + s]);
                } else {
                    #pragma unroll
                    for (int s = 0; s < 16; ++s) e[s] = 0.f;
                }
                #pragma unroll
                for (int s = 0; s < 16; ++s) val[s] = al * tv[s] + be * e[s];
                // off-diagonal tile: no diag term possible
            }
            short8 h0, h1, l0, l1;
            #pragma unroll
            for (int c = 0; c < 8; ++c) {
                unsigned short h = f2bf(val[c]);
                h0[c] = (short)h; l0[c] = (short)f2bf(val[c] - bf2f(h));
                unsigned short h2 = f2bf(val[c + 8]);
                h1[c] = (short)h2; l1[c] = (short)f2bf(val[c + 8] - bf2f(h2));
            }
            size_t cb = (size_t)bl * CC * CC + (size_t)grm * CC + gcm;
            *(short8*)&Ch[cb] = h0; *(short8*)&Ch[cb + 8] = h1;
            *(short8*)&Cl[cb] = l0; *(short8*)&Cl[cb + 8] = l1;
        }
        __syncthreads();   // protect ep before next band overwrites
    }
}

// ---------------------------------------------------------------------------
// Schedule (chunk of g batches, 4 slots of g*256KB in d_ws):
//   scalars (mu,pw,inv,snorm,invs) live in the TAIL of d_out; the tail is
//   overwritten only by the last chunk's final GEMM (after all scalar reads).
//   s3 initially holds split-X (xh,xl); dead after cov; Y2' overwrites it.
// ---------------------------------------------------------------------------
extern "C" void kernel_launch(void* const* d_in, const int* in_sizes, int n_in,
                              void* d_out, int out_size, void* d_ws, size_t ws_size,
                              hipStream_t stream) {
    const float* x = (const float*)d_in[0];
    float* out = (float*)d_out;
    char* ws = (char*)d_ws;

    const int SCR = 2 * BB * CC + 3 * BB;          // 131840 floats
    float* mu    = out + (out_size - SCR);
    float* pw    = mu + BB * CC;
    float* inv   = pw + BB * CC;
    float* snorm = inv + BB;
    float* invs  = snorm + BB;

    size_t per_b = 4ull * CC * CC * 4;             // 1 MiB of ws per batch
    int gmax = (int)(ws_size / per_b);
    int g = 1;
    while (g * 2 <= gmax && g * 2 <= BB) g *= 2;

    size_t slotb = (size_t)g * CC * CC * 4;        // bytes per slot
    auto HI = [&](int s) { return (unsigned short*)(ws + s * slotb); };
    auto LO = [&](int s) { return (unsigned short*)(ws + s * slotb + slotb / 2); };
    unsigned short* xh = (unsigned short*)(ws + 3 * slotb);   // in s3
    unsigned short* xl = xh + (size_t)g * CC * KP;

    meanpow_kernel<<<BB * CC / 4, 256, 0, stream>>>(x, mu, pw);
    norm_kernel<<<BB, 256, 0, stream>>>(mu, pw, inv, snorm, invs);

    for (int b0 = 0; b0 < BB; b0 += g) {
        splitx_kernel<<<dim3(56, g), 256, 0, stream>>>(x, xh, xl, b0);
        // A = ((X@X^T)/M - mu mu^T) / normA  -> s0 (hi/lo)
        mm_kernel<0><<<g * 3, 256, 0, stream>>>(xh, xl, xh, xl, nullptr, nullptr,
            HI(0), LO(0), mu, inv, nullptr, 0.f, 0.f, 0.f, b0);
        // Y1 = -0.5*(A@A) + 1.5*A -> s1
        mm_kernel<1><<<g * 3, 256, 0, stream>>>(HI(0), LO(0), HI(0), LO(0), HI(0), LO(0),
            HI(1), LO(1), nullptr, nullptr, nullptr, -0.5f, 1.5f, 0.f, b0);
        // ZY1 = 0.25*(A@Y1) - 0.75*Y1 + 1.5I -> s2
        mm_kernel<1><<<g * 3, 256, 0, stream>>>(HI(0), LO(0), HI(1), LO(1), HI(1), LO(1),
            HI(2), LO(2), nullptr, nullptr, nullptr, 0.25f, -0.75f, 1.5f, b0);
        // Y2' = snorm * (Y1@ZY1) -> s3 (split-X dead)
        mm_kernel<1><<<g * 3, 256, 0, stream>>>(HI(1), LO(1), HI(2), LO(2), nullptr, nullptr,
            HI(3), LO(3), nullptr, nullptr, snorm, 1.f, 0.f, 0.f, b0);
        // Z2' = invs * (-0.5*(ZY1@A) + 1.5*ZY1) -> s1
        mm_kernel<1><<<g * 3, 256, 0, stream>>>(HI(2), LO(2), HI(0), LO(0), HI(2), LO(2),
            HI(1), LO(1), nullptr, nullptr, invs, -0.5f, 1.5f, 0.f, b0);
        // T = -0.5*(Z2'@Y2') + 1.5I -> s0
        mm_kernel<1><<<g * 3, 256, 0, stream>>>(HI(1), LO(1), HI(3), LO(3), nullptr, nullptr,
            HI(0), LO(0), nullptr, nullptr, nullptr, -0.5f, 0.f, 1.5f, b0);
        // out = triu(Y2'@T)
        mm_kernel<2><<<g * 3, 256, 0, stream>>>(HI(3), LO(3), HI(0), LO(0), nullptr, nullptr,
            out, nullptr, nullptr, nullptr, nullptr, 1.f, 0.f, 0.f, b0);
    }
}

// Round 5
// 1091.473 us; speedup vs baseline: 1.0779x; 1.0779x over previous
//
#include <hip/hip_runtime.h>
#include <math.h>

// ---------------------------------------------------------------------------
// MPNCOV / iSQRT-COV, split-bf16 MFMA implementation.
//   All matrices stored as bf16 (hi, lo) pairs; products use 3 MFMA terms
//   (AhBh + AhBl + AlBh) with fp32 accumulation (~2^-17 rel err).
//   All NS matrices symmetric -> operands staged k-major by reading ROWS
//   (global_load_lds width=16, raw bytes), triu tiles only, t01 mirrored.
//   R5: fully coalesced epilogue (128B-contiguous stores, short8 E loads).
// ---------------------------------------------------------------------------

#define BB 256
#define CC 256
#define MN 196
#define KP 224            // X padded K (7 * 32) for the cov GEMM
#define TRI 32896

typedef __attribute__((ext_vector_type(8))) short short8;   // 8 bf16 = 4 VGPR
typedef __attribute__((ext_vector_type(4))) float f32x4;

__device__ __forceinline__ unsigned short f2bf(float x) {   // RNE fp32->bf16
    unsigned u = __float_as_uint(x);
    u += 0x7fffu + ((u >> 16) & 1u);
    return (unsigned short)(u >> 16);
}
__device__ __forceinline__ float bf2f(unsigned short h) {
    return __uint_as_float(((unsigned)h) << 16);
}
__device__ __forceinline__ void async16(const void* g, void* l) {
    __builtin_amdgcn_global_load_lds(
        (const __attribute__((address_space(1))) unsigned char*)g,
        (__attribute__((address_space(3))) unsigned char*)l, 16, 0, 0);
}

// ---------------------------------------------------------------------------
__global__ __launch_bounds__(256) void meanpow_kernel(const float* __restrict__ x,
                                                      float* __restrict__ mu,
                                                      float* __restrict__ pw) {
    int wave = (blockIdx.x * 256 + threadIdx.x) >> 6;
    int lane = threadIdx.x & 63;
    const float* row = x + (size_t)wave * MN;
    float a0 = row[lane], a1 = row[lane + 64], a2 = row[lane + 128];
    float a3 = (lane < MN - 192) ? row[lane + 192] : 0.0f;
    float s  = a0 + a1 + a2 + a3;
    float ss = a0 * a0 + a1 * a1 + a2 * a2 + a3 * a3;
    #pragma unroll
    for (int off = 32; off > 0; off >>= 1) {
        s  += __shfl_down(s, off, 64);
        ss += __shfl_down(ss, off, 64);
    }
    if (lane == 0) { mu[wave] = s * (1.0f / MN); pw[wave] = ss; }
}

// ---------------------------------------------------------------------------
__global__ __launch_bounds__(256) void norm_kernel(const float* __restrict__ mu,
                                                   const float* __restrict__ pw,
                                                   float* __restrict__ inv,
                                                   float* __restrict__ snorm,
                                                   float* __restrict__ invs) {
    __shared__ float red[256];
    int b = blockIdx.x, i = threadIdx.x;
    float m = mu[b * CC + i];
    red[i] = pw[b * CC + i] * (1.0f / MN) - m * m;
    __syncthreads();
    for (int s = 128; s > 0; s >>= 1) {
        if (i < s) red[i] += red[i + s];
        __syncthreads();
    }
    if (i == 0) {
        float n = red[0];
        inv[b] = 1.0f / n;
        float sq = sqrtf(n);
        snorm[b] = sq;
        invs[b] = 1.0f / sq;
    }
}

// ---------------------------------------------------------------------------
__global__ __launch_bounds__(256) void splitx_kernel(const float* __restrict__ x,
                                                     unsigned short* __restrict__ xh,
                                                     unsigned short* __restrict__ xl,
                                                     int b0) {
    int t = blockIdx.x * 256 + threadIdx.x;      // row*56 + k4, t < 14336
    int row = t / 56;
    int k4 = t - row * 56;
    const float* xr = x + ((size_t)(b0 + blockIdx.y) * CC + row) * MN;
    unsigned long long ph = 0, pl = 0;
    #pragma unroll
    for (int i = 0; i < 4; ++i) {
        int k = k4 * 4 + i;
        float xv = (k < MN) ? xr[k] : 0.0f;
        unsigned short h = f2bf(xv);
        unsigned short l = f2bf(xv - bf2f(h));
        ph |= ((unsigned long long)h) << (16 * i);
        pl |= ((unsigned long long)l) << (16 * i);
    }
    size_t o = ((size_t)blockIdx.y * CC + row) * KP + k4 * 4;
    *(unsigned long long*)&xh[o] = ph;
    *(unsigned long long*)&xl[o] = pl;
}

// ---------------------------------------------------------------------------
// Split-bf16 MFMA GEMM.  MODE 0: cov->A epilogue (K=224, mu/inv),
// MODE 1: NS epilogue  C = al*(A@B) + be*E + diag*I (al/be opt * Sg[bg]),
// MODE 2: FINAL  out(triu fp32) = A@B.
// 128x128 tile, 4 waves, wave = 64x64 = 4x4 frags of 16x16x32 bf16 MFMA.
// Epilogue: per-band LDS transpose (stride 72, conflict-free reads) so every
// global store is 16B/lane with 8 lanes contiguous (128B lines) — direct
// phase banded by rows, mirror phase banded by cols.
// ---------------------------------------------------------------------------
template <int MODE>
__global__ __launch_bounds__(256, 3) void mm_kernel(
    const unsigned short* __restrict__ Ahg, const unsigned short* __restrict__ Alg,
    const unsigned short* __restrict__ Bhg, const unsigned short* __restrict__ Blg,
    const unsigned short* __restrict__ Ehg, const unsigned short* __restrict__ Elg,
    void* __restrict__ Cho, void* __restrict__ Clo,
    const float* __restrict__ mu, const float* __restrict__ inv,
    const float* __restrict__ Sg,
    float alpha0, float beta0, float diag_add, int b0)
{
    constexpr int KD = (MODE == 0) ? KP : CC;
    constexpr int NK = KD / 32;
    __shared__ __align__(16) unsigned short Ah[128 * 32];
    __shared__ __align__(16) unsigned short Al[128 * 32];
    __shared__ __align__(16) unsigned short Bh[128 * 32];
    __shared__ __align__(16) unsigned short Bl[128 * 32];
    __shared__ __align__(16) float eps[4][16 * 72];

    const int bl = blockIdx.x / 3;
    const int t  = blockIdx.x - 3 * bl;
    const int bg = b0 + bl;
    const int ti = (t == 2) ? 1 : 0;
    const int tj = (t == 0) ? 0 : 1;
    const int tid = threadIdx.x;
    const int w = tid >> 6, lane = tid & 63;
    const int wr = w >> 1, wc = w & 1;
    const int m15 = lane & 15, q = lane >> 4;
    const int srow = lane >> 2;          // staging: 16-row chunk, 4 lanes/row
    const int scol = (lane & 3) * 8;     // staging: 8-bf16 (16B) sub-chunk

    // wave-uniform branch select (NO pointer arrays: LDS-pointer arrays
    // fail to compile on gfx950)
    const size_t aoff = (size_t)bl * CC * KD + (size_t)(ti * 128) * KD;
    const size_t boff = (size_t)bl * CC * KD + (size_t)(tj * 128) * KD;
    const unsigned short* gsrc;
    unsigned short* ldst;
    if (w == 0)      { gsrc = Ahg + aoff; ldst = Ah; }
    else if (w == 1) { gsrc = Alg + aoff; ldst = Al; }
    else if (w == 2) { gsrc = Bhg + boff; ldst = Bh; }
    else             { gsrc = Blg + boff; ldst = Bl; }

    f32x4 acc[4][4];
    #pragma unroll
    for (int mi = 0; mi < 4; ++mi)
        #pragma unroll
        for (int ni = 0; ni < 4; ++ni) acc[mi][ni] = (f32x4){0.f, 0.f, 0.f, 0.f};

    #pragma unroll 1
    for (int ks = 0; ks < NK; ++ks) {
        const int k0 = ks * 32;
        __syncthreads();
        #pragma unroll
        for (int tt = 0; tt < 8; ++tt)
            async16(gsrc + (size_t)(tt * 16 + srow) * KD + k0 + scol,
                    ldst + tt * 16 * 32);
        __syncthreads();
        short8 fah[4], fal[4], fbh[4], fbl[4];
        #pragma unroll
        for (int f = 0; f < 4; ++f) {
            int ra = (wr * 64 + f * 16 + m15) * 32 + q * 8;
            int rb = (wc * 64 + f * 16 + m15) * 32 + q * 8;
            fah[f] = *(const short8*)&Ah[ra];
            fal[f] = *(const short8*)&Al[ra];
            fbh[f] = *(const short8*)&Bh[rb];
            fbl[f] = *(const short8*)&Bl[rb];
        }
        // 3-term split product: AhBh + AhBl + AlBh  (AlBl ~ 2^-18, dropped)
        #pragma unroll
        for (int mi = 0; mi < 4; ++mi)
            #pragma unroll
            for (int ni = 0; ni < 4; ++ni) {
                acc[mi][ni] = __builtin_amdgcn_mfma_f32_16x16x32_bf16(fal[mi], fbh[ni], acc[mi][ni], 0, 0, 0);
                acc[mi][ni] = __builtin_amdgcn_mfma_f32_16x16x32_bf16(fah[mi], fbl[ni], acc[mi][ni], 0, 0, 0);
                acc[mi][ni] = __builtin_amdgcn_mfma_f32_16x16x32_bf16(fah[mi], fbh[ni], acc[mi][ni], 0, 0, 0);
            }
    }

    // ---------------- epilogue -------------------------------------------
    float* ep = eps[w];
    unsigned short* Ch = (unsigned short*)Cho;
    unsigned short* Cl = (unsigned short*)Clo;

    float ivv = 0.f, ivm = 0.f, al = alpha0, be = beta0;
    if (MODE == 0) { ivv = inv[bg]; ivm = ivv * (1.0f / MN); }
    if (MODE == 1 && Sg != nullptr) { float s = Sg[bg]; al *= s; be *= s; }

    // ---- phase 1: direct tile, banded by 16-row groups (mi) ----
    #pragma unroll 1
    for (int mi = 0; mi < 4; ++mi) {
        // dump band: ep[rr*72 + cc] = tile[mi*16+rr][cc]
        #pragma unroll
        for (int ni = 0; ni < 4; ++ni)
            #pragma unroll
            for (int r = 0; r < 4; ++r)
                ep[(q * 4 + r) * 72 + ni * 16 + m15] = acc[mi][ni][r];
        // (within-wave RAW: compiler lgkmcnt)
        #pragma unroll
        for (int it = 0; it < 2; ++it) {
            const int r8 = lane >> 3, c8 = lane & 7;
            const int rloc = it * 8 + r8;
            float v[8];
            #pragma unroll
            for (int k = 0; k < 8; ++k) v[k] = ep[rloc * 72 + c8 * 8 + k];
            const int gr = ti * 128 + wr * 64 + mi * 16 + rloc;
            const int gc = tj * 128 + wc * 64 + c8 * 8;

            if (MODE == 2) {
                float* outp = (float*)Cho;
                int rowbase = gr * CC - (gr * (gr - 1)) / 2 - gr;
                float* ob = outp + (size_t)bg * TRI + rowbase;
                #pragma unroll
                for (int k = 0; k < 8; ++k)
                    if (gc + k >= gr) ob[gc + k] = v[k];
            } else {
                float val[8];
                if (MODE == 0) {
                    float mr = mu[bg * CC + gr] * ivv;
                    const float* mcp = &mu[bg * CC + gc];
                    #pragma unroll
                    for (int k = 0; k < 8; ++k)
                        val[k] = v[k] * ivm - mr * mcp[k];
                } else {
                    size_t eb = (size_t)bl * CC * CC + (size_t)gr * CC + gc;
                    if (Ehg != nullptr) {
                        short8 eh = *(const short8*)&Ehg[eb];
                        short8 el = *(const short8*)&Elg[eb];
                        #pragma unroll
                        for (int k = 0; k < 8; ++k)
                            val[k] = al * v[k] +
                                     be * (bf2f((unsigned short)eh[k]) +
                                           bf2f((unsigned short)el[k]));
                    } else {
                        #pragma unroll
                        for (int k = 0; k < 8; ++k) val[k] = al * v[k];
                    }
                    int d = gr - gc;
                    if (d >= 0 && d < 8) val[d] += diag_add;
                }
                short8 hv, lv;
                #pragma unroll
                for (int k = 0; k < 8; ++k) {
                    unsigned short h = f2bf(val[k]);
                    hv[k] = (short)h;
                    lv[k] = (short)f2bf(val[k] - bf2f(h));
                }
                size_t cb = (size_t)bl * CC * CC + (size_t)gr * CC + gc;
                *(short8*)&Ch[cb] = hv;
                *(short8*)&Cl[cb] = lv;
            }
        }
        __syncthreads();   // WAR: band reuse of ep
    }

    // ---- phase 2: mirror tile (t01 only), banded by 16-col groups (ni) ----
    if (MODE != 2 && ti != tj) {
        #pragma unroll 1
        for (int ni = 0; ni < 4; ++ni) {
            // transposed dump: ep[cloc*72 + rr] = tile[rr][ni*16+cloc]
            #pragma unroll
            for (int mi = 0; mi < 4; ++mi)
                #pragma unroll
                for (int r = 0; r < 4; ++r)
                    ep[m15 * 72 + mi * 16 + q * 4 + r] = acc[mi][ni][r];
            #pragma unroll
            for (int it = 0; it < 2; ++it) {
                const int rm = lane >> 2;              // mirror-local row 0..15
                const int ch = (lane & 3) + it * 4;    // 8-elem col chunk 0..7
                float v[8];
                #pragma unroll
                for (int k = 0; k < 8; ++k) v[k] = ep[rm * 72 + ch * 8 + k];
                const int grm = tj * 128 + wc * 64 + ni * 16 + rm;
                const int gcm = ti * 128 + wr * 64 + ch * 8;
                float val[8];
                if (MODE == 0) {
                    float mr = mu[bg * CC + grm] * ivv;
                    const float* mcp = &mu[bg * CC + gcm];
                    #pragma unroll
                    for (int k = 0; k < 8; ++k)
                        val[k] = v[k] * ivm - mr * mcp[k];
                } else {
                    size_t eb = (size_t)bl * CC * CC + (size_t)grm * CC + gcm;
                    if (Ehg != nullptr) {
                        short8 eh = *(const short8*)&Ehg[eb];
                        short8 el = *(const short8*)&Elg[eb];
                        #pragma unroll
                        for (int k = 0; k < 8; ++k)
                            val[k] = al * v[k] +
                                     be * (bf2f((unsigned short)eh[k]) +
                                           bf2f((unsigned short)el[k]));
                    } else {
                        #pragma unroll
                        for (int k = 0; k < 8; ++k) val[k] = al * v[k];
                    }
                    // off-diagonal quadrant: no diag term
                }
                short8 hv, lv;
                #pragma unroll
                for (int k = 0; k < 8; ++k) {
                    unsigned short h = f2bf(val[k]);
                    hv[k] = (short)h;
                    lv[k] = (short)f2bf(val[k] - bf2f(h));
                }
                size_t cb = (size_t)bl * CC * CC + (size_t)grm * CC + gcm;
                *(short8*)&Ch[cb] = hv;
                *(short8*)&Cl[cb] = lv;
            }
            __syncthreads();
        }
    }
}

// ---------------------------------------------------------------------------
// Schedule per chunk of g batches (4 slots of g*256KB in d_ws):
//   A  = cov/n;  Y1 = -0.5 A@A + 1.5 A;  ZY1 = 0.25 A@Y1 - 0.75 Y1 + 1.5 I;
//   Y2'= sqrt(n)(Y1@ZY1);  Z2' = (1/sqrt n)(-0.5 ZY1@A + 1.5 ZY1);
//   T  = -0.5 Z2'@Y2' + 1.5 I;  out = triu(Y2'@T).
// Scalars (mu,pw,inv,snorm,invs) live in the TAIL of d_out (overwritten only
// by the last chunk's final GEMM). Split-X lives in s3 until Y2' overwrites.
// ---------------------------------------------------------------------------
extern "C" void kernel_launch(void* const* d_in, const int* in_sizes, int n_in,
                              void* d_out, int out_size, void* d_ws, size_t ws_size,
                              hipStream_t stream) {
    const float* x = (const float*)d_in[0];
    float* out = (float*)d_out;
    char* ws = (char*)d_ws;

    const int SCR = 2 * BB * CC + 3 * BB;          // 131840 floats
    float* mu    = out + (out_size - SCR);
    float* pw    = mu + BB * CC;
    float* inv   = pw + BB * CC;
    float* snorm = inv + BB;
    float* invs  = snorm + BB;

    size_t per_b = 4ull * CC * CC * 4;             // 1 MiB of ws per batch
    int gmax = (int)(ws_size / per_b);
    int g = 1;
    while (g * 2 <= gmax && g * 2 <= BB) g *= 2;

    size_t slotb = (size_t)g * CC * CC * 4;        // bytes per slot
    auto HI = [&](int s) { return (unsigned short*)(ws + s * slotb); };
    auto LO = [&](int s) { return (unsigned short*)(ws + s * slotb + slotb / 2); };
    unsigned short* xh = (unsigned short*)(ws + 3 * slotb);   // in s3
    unsigned short* xl = xh + (size_t)g * CC * KP;

    meanpow_kernel<<<BB * CC / 4, 256, 0, stream>>>(x, mu, pw);
    norm_kernel<<<BB, 256, 0, stream>>>(mu, pw, inv, snorm, invs);

    for (int b0 = 0; b0 < BB; b0 += g) {
        splitx_kernel<<<dim3(56, g), 256, 0, stream>>>(x, xh, xl, b0);
        // A = ((X@X^T)/M - mu mu^T) / normA  -> s0 (hi/lo)
        mm_kernel<0><<<g * 3, 256, 0, stream>>>(xh, xl, xh, xl, nullptr, nullptr,
            HI(0), LO(0), mu, inv, nullptr, 0.f, 0.f, 0.f, b0);
        // Y1 = -0.5*(A@A) + 1.5*A -> s1
        mm_kernel<1><<<g * 3, 256, 0, stream>>>(HI(0), LO(0), HI(0), LO(0), HI(0), LO(0),
            HI(1), LO(1), nullptr, nullptr, nullptr, -0.5f, 1.5f, 0.f, b0);
        // ZY1 = 0.25*(A@Y1) - 0.75*Y1 + 1.5I -> s2
        mm_kernel<1><<<g * 3, 256, 0, stream>>>(HI(0), LO(0), HI(1), LO(1), HI(1), LO(1),
            HI(2), LO(2), nullptr, nullptr, nullptr, 0.25f, -0.75f, 1.5f, b0);
        // Y2' = snorm * (Y1@ZY1) -> s3 (split-X dead)
        mm_kernel<1><<<g * 3, 256, 0, stream>>>(HI(1), LO(1), HI(2), LO(2), nullptr, nullptr,
            HI(3), LO(3), nullptr, nullptr, snorm, 1.f, 0.f, 0.f, b0);
        // Z2' = invs * (-0.5*(ZY1@A) + 1.5*ZY1) -> s1
        mm_kernel<1><<<g * 3, 256, 0, stream>>>(HI(2), LO(2), HI(0), LO(0), HI(2), LO(2),
            HI(1), LO(1), nullptr, nullptr, invs, -0.5f, 1.5f, 0.f, b0);
        // T = -0.5*(Z2'@Y2') + 1.5I -> s0
        mm_kernel<1><<<g * 3, 256, 0, stream>>>(HI(1), LO(1), HI(3), LO(3), nullptr, nullptr,
            HI(0), LO(0), nullptr, nullptr, nullptr, -0.5f, 0.f, 1.5f, b0);
        // out = triu(Y2'@T)
        mm_kernel<2><<<g * 3, 256, 0, stream>>>(HI(3), LO(3), HI(0), LO(0), nullptr, nullptr,
            out, nullptr, nullptr, nullptr, nullptr, 1.f, 0.f, 0.f, b0);
    }
}

// Round 6
// 960.337 us; speedup vs baseline: 1.2251x; 1.1366x over previous
//
#include <hip/hip_runtime.h>
#include <math.h>

// ---------------------------------------------------------------------------
// MPNCOV / iSQRT-COV, split-bf16 MFMA, packed hi|lo storage (1 u32 / element).
//   value(elem) = bf2f(hi) + bf2f(lo); products use 3 MFMA terms
//   (AhBh + AhBl + AlBh), fp32 accumulation (~2^-17 rel).
//   All chain matrices symmetric: operands staged k-major by reading ROWS via
//   global_load_lds w=16 (XOR chunk swizzle for conflict-free frag reads),
//   upper 128x128 tiles only, t01 mirror-written. Z1 = 1.5I-0.5A materialized
//   in the cov epilogue so every NS step is a PURE GEMM (no E reads).
// ---------------------------------------------------------------------------

#define BB 256
#define CC 256
#define MN 196
#define KP 224            // X padded K (7*32) for the cov GEMM
#define TRI 32896
#define EPS_S 76          // eps row stride (words), 16B-aligned, de-conflicted

typedef __attribute__((ext_vector_type(8))) short short8;   // 8 bf16
typedef __attribute__((ext_vector_type(4))) float f32x4;
typedef __attribute__((ext_vector_type(4))) unsigned int u32x4;

__device__ __forceinline__ unsigned short f2bf(float x) {   // RNE fp32->bf16
    unsigned u = __float_as_uint(x);
    u += 0x7fffu + ((u >> 16) & 1u);
    return (unsigned short)(u >> 16);
}
__device__ __forceinline__ float bf2f(unsigned short h) {
    return __uint_as_float(((unsigned)h) << 16);
}
__device__ __forceinline__ unsigned packsplit(float x) {    // hi|lo in one u32
    unsigned short h = f2bf(x);
    unsigned short l = f2bf(x - bf2f(h));
    return (((unsigned)h) << 16) | (unsigned)l;
}
__device__ __forceinline__ void async16(const void* g, void* l) {
    __builtin_amdgcn_global_load_lds(
        (const __attribute__((address_space(1))) unsigned char*)g,
        (__attribute__((address_space(3))) unsigned char*)l, 16, 0, 0);
}

// ---------------------------------------------------------------------------
__global__ __launch_bounds__(256) void meanpow_kernel(const float* __restrict__ x,
                                                      float* __restrict__ mu,
                                                      float* __restrict__ pw) {
    int wave = (blockIdx.x * 256 + threadIdx.x) >> 6;
    int lane = threadIdx.x & 63;
    const float* row = x + (size_t)wave * MN;
    float a0 = row[lane], a1 = row[lane + 64], a2 = row[lane + 128];
    float a3 = (lane < MN - 192) ? row[lane + 192] : 0.0f;
    float s  = a0 + a1 + a2 + a3;
    float ss = a0 * a0 + a1 * a1 + a2 * a2 + a3 * a3;
    #pragma unroll
    for (int off = 32; off > 0; off >>= 1) {
        s  += __shfl_down(s, off, 64);
        ss += __shfl_down(ss, off, 64);
    }
    if (lane == 0) { mu[wave] = s * (1.0f / MN); pw[wave] = ss; }
}

// ---------------------------------------------------------------------------
__global__ __launch_bounds__(256) void norm_kernel(const float* __restrict__ mu,
                                                   const float* __restrict__ pw,
                                                   float* __restrict__ inv,
                                                   float* __restrict__ snorm,
                                                   float* __restrict__ invs) {
    __shared__ float red[256];
    int b = blockIdx.x, i = threadIdx.x;
    float m = mu[b * CC + i];
    red[i] = pw[b * CC + i] * (1.0f / MN) - m * m;
    __syncthreads();
    for (int s = 128; s > 0; s >>= 1) {
        if (i < s) red[i] += red[i + s];
        __syncthreads();
    }
    if (i == 0) {
        float n = red[0];
        inv[b] = 1.0f / n;
        float sq = sqrtf(n);
        snorm[b] = sq;
        invs[b] = 1.0f / sq;
    }
}

// ---------------------------------------------------------------------------
// Split x into zero-padded packed hi|lo words: xp[bl][256 rows][224 words]
// ---------------------------------------------------------------------------
__global__ __launch_bounds__(256) void splitx_kernel(const float* __restrict__ x,
                                                     unsigned* __restrict__ xp,
                                                     int b0) {
    int t = blockIdx.x * 256 + threadIdx.x;      // row*56 + k4, t < 14336
    int row = t / 56;
    int k4 = t - row * 56;
    const float* xr = x + ((size_t)(b0 + blockIdx.y) * CC + row) * MN;
    u32x4 wv;
    #pragma unroll
    for (int i = 0; i < 4; ++i) {
        int k = k4 * 4 + i;
        float xv = (k < MN) ? xr[k] : 0.0f;
        wv[i] = packsplit(xv);
    }
    *(u32x4*)&xp[((size_t)blockIdx.y * CC + row) * KP + k4 * 4] = wv;
}

// ---------------------------------------------------------------------------
// Packed split-bf16 MFMA GEMM.
// MODE 0: cov epilogue -> A (Cg) AND Z1 = 1.5I - 0.5A (Zg), K=224, mu/inv.
// MODE 1: C = al*(A@B) + diag*I   (al optionally * Sg[bg]).
// MODE 2: out(triu fp32) = A@B.
// 128x128 tile, 4 waves, wave = 64x64 = 4x4 frags of 16x16x32 bf16 MFMA.
// Staging: global_load_lds w=16 of packed rows, XOR chunk swizzle per row
// (source-side permute) so frag ds_read_b128s are 2-way (free).
// ---------------------------------------------------------------------------
template <int MODE>
__global__ __launch_bounds__(256, 3) void mm_kernel(
    const unsigned* __restrict__ Ag, const unsigned* __restrict__ Bg,
    unsigned* __restrict__ Cg, unsigned* __restrict__ Zg,
    float* __restrict__ outp,
    const float* __restrict__ mu, const float* __restrict__ inv,
    const float* __restrict__ Sg,
    float alpha0, float diag_add, int b0, int swz)
{
    constexpr int KD = (MODE == 0) ? KP : CC;
    constexpr int NK = KD / 32;
    __shared__ __align__(16) unsigned Apk[128 * 32];
    __shared__ __align__(16) unsigned Bpk[128 * 32];
    __shared__ __align__(16) float eps[4][16 * EPS_S];

    // block decode: co-locate a batch's 3 tiles on one XCD (bx%8 heuristic)
    const int bx = blockIdx.x;
    int bl, t;
    if (swz) { int u = bx & 7, v = bx >> 3; bl = (v / 3) * 8 + u; t = v % 3; }
    else     { bl = bx / 3; t = bx - 3 * bl; }
    const int bg = b0 + bl;
    const int ti = (t == 2) ? 1 : 0;
    const int tj = (t == 0) ? 0 : 1;
    const int tid = threadIdx.x;
    const int w = tid >> 6, lane = tid & 63;
    const int wr = w >> 1, wc = w & 1;
    const int m15 = lane & 15, q = lane >> 4;

    // staging lane mapping: 8 rows x 8 chunks(16B) per instruction
    const int row8 = lane >> 3, ch = lane & 7;
    const int sch = ch ^ row8;               // XOR-swizzled source chunk
    const unsigned* gsrc;
    unsigned* ldst;
    {
        const size_t abase = (size_t)bl * CC * KD + (size_t)(ti * 128 + (w & 1) * 64) * KD;
        const size_t bbase = (size_t)bl * CC * KD + (size_t)(tj * 128 + (w & 1) * 64) * KD;
        if (w < 2) { gsrc = Ag + abase; ldst = Apk + (w & 1) * 64 * 32; }
        else       { gsrc = Bg + bbase; ldst = Bpk + (w & 1) * 64 * 32; }
    }

    f32x4 acc[4][4];
    #pragma unroll
    for (int mi = 0; mi < 4; ++mi)
        #pragma unroll
        for (int ni = 0; ni < 4; ++ni) acc[mi][ni] = (f32x4){0.f, 0.f, 0.f, 0.f};

    #pragma unroll 1
    for (int ks = 0; ks < NK; ++ks) {
        const int k0 = ks * 32;
        __syncthreads();
        #pragma unroll
        for (int tt = 0; tt < 8; ++tt)
            async16(gsrc + (size_t)(tt * 8 + row8) * KD + k0 + sch * 4,
                    ldst + tt * 8 * 32);
        __syncthreads();

        short8 fah[4], fal[4], fbh[4], fbl[4];
        #pragma unroll
        for (int f = 0; f < 4; ++f) {
            {
                int r = wr * 64 + f * 16 + m15;
                const unsigned* rp = &Apk[r * 32];
                u32x4 wa = *(const u32x4*)&rp[((2 * q)     ^ (r & 7)) * 4];
                u32x4 wb = *(const u32x4*)&rp[((2 * q + 1) ^ (r & 7)) * 4];
                #pragma unroll
                for (int j = 0; j < 4; ++j) {
                    fah[f][j]     = (short)(wa[j] >> 16);
                    fal[f][j]     = (short)(wa[j] & 0xffffu);
                    fah[f][j + 4] = (short)(wb[j] >> 16);
                    fal[f][j + 4] = (short)(wb[j] & 0xffffu);
                }
            }
            {
                int r = wc * 64 + f * 16 + m15;
                const unsigned* rp = &Bpk[r * 32];
                u32x4 wa = *(const u32x4*)&rp[((2 * q)     ^ (r & 7)) * 4];
                u32x4 wb = *(const u32x4*)&rp[((2 * q + 1) ^ (r & 7)) * 4];
                #pragma unroll
                for (int j = 0; j < 4; ++j) {
                    fbh[f][j]     = (short)(wa[j] >> 16);
                    fbl[f][j]     = (short)(wa[j] & 0xffffu);
                    fbh[f][j + 4] = (short)(wb[j] >> 16);
                    fbl[f][j + 4] = (short)(wb[j] & 0xffffu);
                }
            }
        }
        #pragma unroll
        for (int mi = 0; mi < 4; ++mi)
            #pragma unroll
            for (int ni = 0; ni < 4; ++ni) {
                acc[mi][ni] = __builtin_amdgcn_mfma_f32_16x16x32_bf16(fal[mi], fbh[ni], acc[mi][ni], 0, 0, 0);
                acc[mi][ni] = __builtin_amdgcn_mfma_f32_16x16x32_bf16(fah[mi], fbl[ni], acc[mi][ni], 0, 0, 0);
                acc[mi][ni] = __builtin_amdgcn_mfma_f32_16x16x32_bf16(fah[mi], fbh[ni], acc[mi][ni], 0, 0, 0);
            }
    }

    // ---------------- epilogue (eps is PER-WAVE: same-wave DS ordering,
    // validated in R5 — no barriers needed) -------------------------------
    float* ep = eps[w];
    float al = alpha0;
    float ivv = 0.f, ivm = 0.f;
    if (MODE == 0) { ivv = inv[bg]; ivm = ivv * (1.0f / MN); }
    if (MODE == 1 && Sg != nullptr) al *= Sg[bg];
    const int r4 = lane >> 4, c16 = lane & 15;

    // ---- phase 1: direct tile, banded by 16-row groups (mi) ----
    #pragma unroll 1
    for (int mi = 0; mi < 4; ++mi) {
        #pragma unroll
        for (int ni = 0; ni < 4; ++ni)
            #pragma unroll
            for (int r = 0; r < 4; ++r)
                ep[(q * 4 + r) * EPS_S + ni * 16 + m15] = acc[mi][ni][r];
        #pragma unroll
        for (int it = 0; it < 4; ++it) {
            const int rloc = it * 4 + r4;
            const int gr = ti * 128 + wr * 64 + mi * 16 + rloc;
            const int gc = tj * 128 + wc * 64 + c16 * 4;
            f32x4 v = *(const f32x4*)&ep[rloc * EPS_S + c16 * 4];
            if (MODE == 2) {
                int rowbase = gr * CC - (gr * (gr - 1)) / 2 - gr;
                float* ob = outp + (size_t)bg * TRI + rowbase;
                #pragma unroll
                for (int j = 0; j < 4; ++j)
                    if (gc + j >= gr) ob[gc + j] = v[j];
            } else if (MODE == 0) {
                float mr = mu[bg * CC + gr] * ivv;
                const float* mcp = &mu[bg * CC + gc];
                u32x4 wa, wz;
                #pragma unroll
                for (int j = 0; j < 4; ++j) {
                    float a = v[j] * ivm - mr * mcp[j];
                    float z = ((gr == gc + j) ? 1.5f : 0.0f) - 0.5f * a;
                    wa[j] = packsplit(a);
                    wz[j] = packsplit(z);
                }
                size_t cb = (size_t)bl * CC * CC + (size_t)gr * CC + gc;
                *(u32x4*)&Cg[cb] = wa;
                *(u32x4*)&Zg[cb] = wz;
            } else {
                u32x4 wv;
                #pragma unroll
                for (int j = 0; j < 4; ++j) {
                    float val = al * v[j] + ((gr == gc + j) ? diag_add : 0.0f);
                    wv[j] = packsplit(val);
                }
                size_t cb = (size_t)bl * CC * CC + (size_t)gr * CC + gc;
                *(u32x4*)&Cg[cb] = wv;
            }
        }
    }

    // ---- phase 2: mirror tile (t01 only), banded by 16-col groups (ni) ----
    if (MODE != 2 && ti != tj) {
        #pragma unroll 1
        for (int ni = 0; ni < 4; ++ni) {
            #pragma unroll
            for (int mi = 0; mi < 4; ++mi)
                #pragma unroll
                for (int r = 0; r < 4; ++r)
                    ep[m15 * EPS_S + mi * 16 + q * 4 + r] = acc[mi][ni][r];
            #pragma unroll
            for (int it = 0; it < 4; ++it) {
                const int rloc = it * 4 + r4;
                const int grm = tj * 128 + wc * 64 + ni * 16 + rloc;
                const int gcm = ti * 128 + wr * 64 + c16 * 4;
                f32x4 v = *(const f32x4*)&ep[rloc * EPS_S + c16 * 4];
                size_t cb = (size_t)bl * CC * CC + (size_t)grm * CC + gcm;
                if (MODE == 0) {
                    float mr = mu[bg * CC + grm] * ivv;
                    const float* mcp = &mu[bg * CC + gcm];
                    u32x4 wa, wz;
                    #pragma unroll
                    for (int j = 0; j < 4; ++j) {
                        float a = v[j] * ivm - mr * mcp[j];
                        float z = -0.5f * a;          // off-diagonal quadrant
                        wa[j] = packsplit(a);
                        wz[j] = packsplit(z);
                    }
                    *(u32x4*)&Cg[cb] = wa;
                    *(u32x4*)&Zg[cb] = wz;
                } else {
                    u32x4 wv;
                    #pragma unroll
                    for (int j = 0; j < 4; ++j)
                        wv[j] = packsplit(al * v[j]); // off-diagonal: no diag
                    *(u32x4*)&Cg[cb] = wv;
                }
            }
        }
    }
}

// ---------------------------------------------------------------------------
// Schedule per chunk of g batches (4 packed slots of g*256KB in d_ws):
//   mm<0>:  A -> s0,  Z1 = 1.5I-0.5A -> s1        (reads packed X in s2)
//   mm<1>:  Y1  = A@Z1                  -> s2     (X dead)
//   mm<1>:  ZY1 = -0.5*(Z1@Y1) + 1.5I   -> s3
//   mm<1>:  Y2' = snorm*(Y1@ZY1)        -> s0     (A dead)
//   mm<1>:  Z2' = invs*(ZY1@Z1)         -> s2     (Y1 dead)
//   mm<1>:  T   = -0.5*(Z2'@Y2') + 1.5I -> s1     (Z1,ZY1 dead)
//   mm<2>:  out = triu(Y2'@T)                     (scale folded into Y2')
// Scalars (mu,pw,inv,snorm,invs) live in the TAIL of d_out (only overwritten
// by the last chunk's final GEMM, after all scalar reads — stream-ordered).
// ---------------------------------------------------------------------------
extern "C" void kernel_launch(void* const* d_in, const int* in_sizes, int n_in,
                              void* d_out, int out_size, void* d_ws, size_t ws_size,
                              hipStream_t stream) {
    const float* x = (const float*)d_in[0];
    float* out = (float*)d_out;
    char* ws = (char*)d_ws;

    const int SCR = 2 * BB * CC + 3 * BB;          // 131840 floats
    float* mu    = out + (out_size - SCR);
    float* pw    = mu + BB * CC;
    float* inv   = pw + BB * CC;
    float* snorm = inv + BB;
    float* invs  = snorm + BB;

    size_t per_b = 4ull * CC * CC * 4;             // 1 MiB of ws per batch
    int gmax = (int)(ws_size / per_b);
    int g = 1;
    while (g * 2 <= gmax && g * 2 <= BB) g *= 2;
    int swz = (g % 8 == 0) ? 1 : 0;

    size_t slotw = (size_t)g * CC * CC;            // words per slot
    unsigned* S0 = (unsigned*)ws;
    unsigned* S1 = S0 + slotw;
    unsigned* S2 = S0 + 2 * slotw;
    unsigned* S3 = S0 + 3 * slotw;

    meanpow_kernel<<<BB * CC / 4, 256, 0, stream>>>(x, mu, pw);
    norm_kernel<<<BB, 256, 0, stream>>>(mu, pw, inv, snorm, invs);

    for (int b0 = 0; b0 < BB; b0 += g) {
        splitx_kernel<<<dim3(56, g), 256, 0, stream>>>(x, S2, b0);
        // A -> s0, Z1 -> s1
        mm_kernel<0><<<g * 3, 256, 0, stream>>>(S2, S2, S0, S1, nullptr,
            mu, inv, nullptr, 0.f, 0.f, b0, swz);
        // Y1 = A@Z1 -> s2
        mm_kernel<1><<<g * 3, 256, 0, stream>>>(S0, S1, S2, nullptr, nullptr,
            nullptr, nullptr, nullptr, 1.0f, 0.0f, b0, swz);
        // ZY1 = -0.5*(Z1@Y1) + 1.5I -> s3
        mm_kernel<1><<<g * 3, 256, 0, stream>>>(S1, S2, S3, nullptr, nullptr,
            nullptr, nullptr, nullptr, -0.5f, 1.5f, b0, swz);
        // Y2' = snorm*(Y1@ZY1) -> s0
        mm_kernel<1><<<g * 3, 256, 0, stream>>>(S2, S3, S0, nullptr, nullptr,
            nullptr, nullptr, snorm, 1.0f, 0.0f, b0, swz);
        // Z2' = invs*(ZY1@Z1) -> s2
        mm_kernel<1><<<g * 3, 256, 0, stream>>>(S3, S1, S2, nullptr, nullptr,
            nullptr, nullptr, invs, 1.0f, 0.0f, b0, swz);
        // T = -0.5*(Z2'@Y2') + 1.5I -> s1
        mm_kernel<1><<<g * 3, 256, 0, stream>>>(S2, S0, S1, nullptr, nullptr,
            nullptr, nullptr, nullptr, -0.5f, 1.5f, b0, swz);
        // out = triu(Y2'@T)
        mm_kernel<2><<<g * 3, 256, 0, stream>>>(S0, S1, nullptr, nullptr, out,
            nullptr, nullptr, nullptr, 1.0f, 0.0f, b0, swz);
    }
}